// Round 3
// baseline (102.966 us; speedup 1.0000x reference)
//
#include <hip/hip_runtime.h>
#include <hip/hip_bf16.h>
#include <cstdint>

#define KD 512
#define BM 256
#define NT 512
#define LDB 264          // B row stride in ushorts (528 B -> 2-way banks = free)
#define NSPLIT 63
#define NNODES 127

typedef __attribute__((ext_vector_type(8))) short bf16x8;
typedef __attribute__((ext_vector_type(4))) float f32x4;

__device__ __forceinline__ unsigned short f2bf(float f) {
    return __builtin_bit_cast(unsigned short, __float2bfloat16(f));
}
__device__ __forceinline__ float bf2f(unsigned short h) {
    return __builtin_bit_cast(float, (unsigned)h << 16);
}

// 8 fp32 -> bf16 hi + bf16 lo (residual) fragments; compiler pairs casts into v_cvt_pk_bf16_f32
__device__ __forceinline__ void split8(const float* __restrict__ f, bf16x8& h8, bf16x8& l8) {
    union { bf16x8 v; unsigned short s[8]; } H, L;
#pragma unroll
    for (int i = 0; i < 8; ++i) {
        const unsigned short hb = f2bf(f[i]);
        H.s[i] = hb;
        L.s[i] = f2bf(f[i] - bf2f(hb));
    }
    h8 = H.v; l8 = L.v;
}

// x @ A^T via split-bf16 MFMA (hh + lh + hl), x loaded global->reg (no LDS, no
// per-tile barriers); B staged to LDS hi/lo in two K-halves. Fused tree epilogue.
__global__ __launch_bounds__(NT, 4)
void lt_mfma2(const float* __restrict__ x, const float* __restrict__ A,
              float* __restrict__ out) {
    __shared__ __align__(16) unsigned short sm[2 * 64 * LDB];   // 67584 B
    unsigned short* bh = sm;
    unsigned short* bl = sm + 64 * LDB;
    float* fl = reinterpret_cast<float*>(sm);   // epilogue alias

    const int tid  = threadIdx.x;
    const int wave = tid >> 6;
    const int lane = tid & 63;
    const int fr   = lane & 15;            // fragment row (A) / col (B)
    const int kb   = (lane >> 4) * 8;      // fragment k-base
    const int r0   = blockIdx.x * BM;
    const int m0   = wave * 32;            // wave's 32-row slab

    const float* xr0p = x + (size_t)(r0 + m0 + fr) * KD + kb;   // mf=0 row
    const float* xr1p = xr0p + 16 * KD;                          // mf=1 row

    // B staging roles: 8 threads per row, 32 k each
    const int brow = tid >> 3;             // 0..63
    const int bkj  = (tid & 7) * 32;
    const float* ap = A + (size_t)brow * KD + bkj;

    f32x4 acc[2][4];
#pragma unroll
    for (int i = 0; i < 2; ++i)
#pragma unroll
        for (int j = 0; j < 4; ++j) acc[i][j] = (f32x4)(0.f);

    float xb0[2][8], xb1[2][8];            // double-buffered x fragments (fp32)
#pragma unroll
    for (int p = 0; p < 2; ++p) {          // prologue: tile 0
        *reinterpret_cast<float4*>(&xb0[0][p * 4]) =
            *reinterpret_cast<const float4*>(xr0p + p * 4);
        *reinterpret_cast<float4*>(&xb1[0][p * 4]) =
            *reinterpret_cast<const float4*>(xr1p + p * 4);
    }

#pragma unroll
    for (int h = 0; h < 2; ++h) {
        // ---- stage B half h: k in [h*256, h*256+256), hi/lo split, packed 16B writes
#pragma unroll
        for (int p8 = 0; p8 < 4; ++p8) {
            float f[8];
            if (brow < NSPLIT) {
                *reinterpret_cast<float4*>(&f[0]) =
                    *reinterpret_cast<const float4*>(ap + h * 256 + p8 * 8);
                *reinterpret_cast<float4*>(&f[4]) =
                    *reinterpret_cast<const float4*>(ap + h * 256 + p8 * 8 + 4);
            } else {
#pragma unroll
                for (int i = 0; i < 8; ++i) f[i] = 0.f;
            }
            unsigned hw[4], lw[4];
#pragma unroll
            for (int i = 0; i < 4; ++i) {
                const unsigned short h0 = f2bf(f[2 * i]);
                const unsigned short h1 = f2bf(f[2 * i + 1]);
                hw[i] = (unsigned)h0 | ((unsigned)h1 << 16);
                lw[i] = (unsigned)f2bf(f[2 * i]     - bf2f(h0)) |
                        ((unsigned)f2bf(f[2 * i + 1] - bf2f(h1)) << 16);
            }
            *reinterpret_cast<int4*>(&bh[brow * LDB + bkj + p8 * 8]) =
                *reinterpret_cast<int4*>(hw);
            *reinterpret_cast<int4*>(&bl[brow * LDB + bkj + p8 * 8]) =
                *reinterpret_cast<int4*>(lw);
        }
        __syncthreads();

        // ---- 8 K-tiles of 32, barrier-free
#pragma unroll
        for (int t = 0; t < 8; ++t) {
            const int gt = h * 8 + t;
            if (gt + 1 < 16) {             // issue next tile's loads first
#pragma unroll
                for (int p = 0; p < 2; ++p) {
                    *reinterpret_cast<float4*>(&xb0[(gt + 1) & 1][p * 4]) =
                        *reinterpret_cast<const float4*>(xr0p + (gt + 1) * 32 + p * 4);
                    *reinterpret_cast<float4*>(&xb1[(gt + 1) & 1][p * 4]) =
                        *reinterpret_cast<const float4*>(xr1p + (gt + 1) * 32 + p * 4);
                }
            }
            bf16x8 ah0, al0, ah1, al1;
            split8(xb0[gt & 1], ah0, al0);
            split8(xb1[gt & 1], ah1, al1);
#pragma unroll
            for (int nf = 0; nf < 4; ++nf) {
                const int off = (nf * 16 + fr) * LDB + t * 32 + kb;
                const bf16x8 bhv = *reinterpret_cast<const bf16x8*>(&bh[off]);
                const bf16x8 blv = *reinterpret_cast<const bf16x8*>(&bl[off]);
                acc[0][nf] = __builtin_amdgcn_mfma_f32_16x16x32_bf16(ah0, bhv, acc[0][nf], 0, 0, 0);
                acc[1][nf] = __builtin_amdgcn_mfma_f32_16x16x32_bf16(ah1, bhv, acc[1][nf], 0, 0, 0);
                acc[0][nf] = __builtin_amdgcn_mfma_f32_16x16x32_bf16(al0, bhv, acc[0][nf], 0, 0, 0);
                acc[1][nf] = __builtin_amdgcn_mfma_f32_16x16x32_bf16(al1, bhv, acc[1][nf], 0, 0, 0);
                acc[0][nf] = __builtin_amdgcn_mfma_f32_16x16x32_bf16(ah0, blv, acc[0][nf], 0, 0, 0);
                acc[1][nf] = __builtin_amdgcn_mfma_f32_16x16x32_bf16(ah1, blv, acc[1][nf], 0, 0, 0);
            }
        }
        __syncthreads();
    }

    // ---- epilogue: per wave, 2 phases of 16 rows via LDS [16][65] (aliases B area)
    const int drow = (lane >> 4) * 4;      // D-frag: row = drow+rg, col = fr
    float* warea = fl + wave * 16 * 65;
    const int trow = lane >> 2;            // 4 lanes per row
    const int part = lane & 3;             // lane stores nodes [part*32, part*32+32)

#pragma unroll
    for (int ph = 0; ph < 2; ++ph) {
#pragma unroll
        for (int nf = 0; nf < 4; ++nf)
#pragma unroll
            for (int rg = 0; rg < 4; ++rg)
                warea[(drow + rg) * 65 + nf * 16 + fr] = acc[ph][nf][rg];
        __syncthreads();

        const float* srowp = warea + trow * 65;
        float* orow = out + (size_t)(r0 + m0 + ph * 16 + trow) * NNODES;
        float q[NNODES];                   // static indices only -> registers
        q[0] = 1.f;
        if (part == 0) orow[0] = 1.f;
#pragma unroll
        for (int t = 0; t < NSPLIT; ++t) {
            const float s  = srowp[t];
            const float ql = fminf(q[t], s);
            const float qr = fminf(q[t], -s);
            q[2 * t + 1] = ql;
            q[2 * t + 2] = qr;
            const float zl = fminf(fmaxf(ql, 0.f), 1.f);
            const float zr = fminf(fmaxf(qr, 0.f), 1.f);
            if (((2 * t + 1) >> 5) == part) orow[2 * t + 1] = zl;
            if (((2 * t + 2) >> 5) == part) orow[2 * t + 2] = zr;
        }
        __syncthreads();
    }
}

extern "C" void kernel_launch(void* const* d_in, const int* in_sizes, int n_in,
                              void* d_out, int out_size, void* d_ws, size_t ws_size,
                              hipStream_t stream) {
    const float* x = (const float*)d_in[0];   // [131072, 512]
    const float* A = (const float*)d_in[1];   // [63, 512]
    float* out = (float*)d_out;               // [131072, 127]
    const int nrows = in_sizes[0] / KD;       // 131072
    const int grid = nrows / BM;              // 512 blocks = exactly 2/CU
    lt_mfma2<<<dim3(grid), dim3(NT), 0, stream>>>(x, A, out);
}